// Round 5
// baseline (121.645 us; speedup 1.0000x reference)
//
#include <hip/hip_runtime.h>

// MatchSegmentation, single fused worker dispatch.
// ce[k,g] = -( sum_{n: gt=1} d[k,n] + sum_n l1[k,n] ) / N,  d = lp - l1.
// Accumulated in log2 domain (uniform positive scale preserves both argmins).
//
// R16: R15 post-mortem -- NBLK 1008 re-walked R10's known-bad direction
// (fixed per-block costs amortized over half the work, reduce set doubled):
// that was the +8-10; fusion/prefetch were ~-2. Revert to NBLK=504/NITER=10
// (R14 = 92.6 best) and instead delete the remaining dispatch overhead:
//  - accum blocks atomicAdd 336 partials straight into global acc
//    (336 addrs across LLC channels, ~504-way each, pipelined ~1-2us,
//    hidden in kernel tail) -- removes partial write + reduce kernel.
//  - last-block ticket (R15-proven, cross-XCD-safe RMW re-reads) runs
//    finalize in the SAME dispatch. 3 dispatches -> memset + 1.
//  - keep seg cross-iter prefetch.
// Risk: atomic sum order nondeterministic (~5e-8 on ce); argmin gaps are
// orders larger (log2-rewrite already survived). If absmax!=0 -> revert.
// Predict: 92.6 -> 84-89us. If >=92: dispatch overhead not the cost ->
// accum itself is ~85us of clock-ramp; profile-split or declare.

#define N_PIX    230400
#define K_SEG    21
#define NG       15                 // gt_plane_num in this harness
#define NPB      (N_PIX / 4)        // 57600 pixel-blocks
#define NBLK     504                // R10: NBLK gradient bottoms here
#define NTHREADS 256
#define TOT_THR  (NBLK * NTHREADS)  // 129024
#define PB_STRIDE (TOT_THR / K_SEG) // 6144
#define NITER    ((NPB + PB_STRIDE - 1) / PB_STRIDE)  // 10
#define NPB_BLK  14                 // distinct pb slots per block per iter
#define NSLOT    (K_SEG * NG + K_SEG)  // 315 d-sums ++ 21 l1-sums = 336
#define EPSF     1e-6f
#define BIGF     1.0e6f

typedef float f32x2 __attribute__((ext_vector_type(2)));
typedef float f32x4 __attribute__((ext_vector_type(4)));

__device__ __forceinline__ void pk_fma(f32x2& a, f32x2 m, f32x2 d) {
    // a += m * d, packed 2x fp32 in one instruction
    asm("v_pk_fma_f32 %0, %1, %2, %0" : "+v"(a) : "v"(m), "v"(d));
}

union SMem {
    f32x4 gtf[NITER][NG][NPB_BLK];   // 33.6 KB -- live in phase 1 only
    float part[NTHREADS][NG + 2];    // 17.4 KB -- live in phase 2 only
};

__global__ __launch_bounds__(NTHREADS, 2)
void ce_fused_kernel(const float* __restrict__ seg,    // (N, 21) fp32
                     const int*   __restrict__ gt,     // (21, N) int32 {0,1}
                     const int*   __restrict__ gpn_ptr,
                     int*         __restrict__ out,    // (21,) int32
                     float*       __restrict__ acc,    // [NSLOT], pre-zeroed
                     unsigned int* __restrict__ counter) // pre-zeroed
{
    __shared__ SMem sm;
    __shared__ unsigned int rank;
    __shared__ float s_acc   [NSLOT];
    __shared__ float ce_val  [K_SEG];
    __shared__ int   matching[K_SEG];
    __shared__ int   best_k  [NG];
    __shared__ int   max_index_s;

    const int t    = threadIdx.x;
    const int u0   = blockIdx.x * NTHREADS + t;
    const int k    = u0 % K_SEG;                      // fixed per thread
    const int pbt  = u0 / K_SEG;                      // pb at j=0
    const int pb0b = (blockIdx.x * NTHREADS) / K_SEG; // block's first pb
    const int didx = pbt - pb0b;                      // 0..13, constant over j

    const int4* gt4 = (const int4*)gt;                // plane stride NPB int4s

    // ---- prologue: stage + convert the block's ENTIRE gt working set ----
    for (int s = t; s < NITER * NG * NPB_BLK; s += NTHREADS) {
        const int j = s / (NG * NPB_BLK);
        const int r = s % (NG * NPB_BLK);
        const int g = r / NPB_BLK;
        const int o = r % NPB_BLK;
        const int ps = pb0b + o + j * PB_STRIDE;
        f32x4 f = {0.0f, 0.0f, 0.0f, 0.0f};
        if (ps < NPB) {
            int4 m = gt4[(size_t)g * NPB + ps];       // coalesced 224B runs
            f = f32x4{(float)m.x, (float)m.y, (float)m.z, (float)m.w};
        }
        sm.gtf[j][g][o] = f;
    }

    // issue j=0 seg loads BEFORE the barrier (independent of LDS staging)
    const size_t base0 = (size_t)pbt * (4 * K_SEG) + k;   // pbt < NPB at j=0
    float ns0 = seg[base0];
    float ns1 = seg[base0 + K_SEG];
    float ns2 = seg[base0 + 2 * K_SEG];
    float ns3 = seg[base0 + 3 * K_SEG];

    f32x2 acc_r[NG];
    #pragma unroll
    for (int g = 0; g < NG; ++g) acc_r[g] = f32x2{0.0f, 0.0f};
    f32x2 accl1 = {0.0f, 0.0f};

    __syncthreads();                                  // gtf staged

    #pragma unroll
    for (int j = 0; j < NITER; ++j) {
        const int  pbj  = pbt + j * PB_STRIDE;
        const bool live = (pbj < NPB);
        const float s0 = ns0, s1 = ns1, s2 = ns2, s3 = ns3;

        // prefetch iter j+1's seg quad (in flight under this iter's compute)
        if (j + 1 < NITER) {
            const int pbn = pbt + (j + 1) * PB_STRIDE;
            if (pbn < NPB) {
                const size_t b2 = (size_t)pbn * (4 * K_SEG) + k;
                ns0 = seg[b2];
                ns1 = seg[b2 + K_SEG];
                ns2 = seg[b2 + 2 * K_SEG];
                ns3 = seg[b2 + 3 * K_SEG];
            }
        }

        if (live) {
            float lp0 = __log2f(s0 + EPSF), l10 = __log2f(1.0f - s0 + EPSF);
            float lp1 = __log2f(s1 + EPSF), l11 = __log2f(1.0f - s1 + EPSF);
            float lp2 = __log2f(s2 + EPSF), l12 = __log2f(1.0f - s2 + EPSF);
            float lp3 = __log2f(s3 + EPSF), l13 = __log2f(1.0f - s3 + EPSF);

            f32x2 d01 = {lp0 - l10, lp1 - l11};
            f32x2 d23 = {lp2 - l12, lp3 - l13};
            accl1 += f32x2{l10, l11};
            accl1 += f32x2{l12, l13};

            // 15 broadcast ds_read_b128 (single addr reg + imm offsets)
            #pragma unroll
            for (int g = 0; g < NG; ++g) {
                f32x4 mm = sm.gtf[j][g][didx];
                pk_fma(acc_r[g], mm.xy, d01);
                pk_fma(acc_r[g], mm.zw, d23);
            }
        }
    }

    __syncthreads();   // all gtf reads complete before aliased part writes

    // ---- non-atomic block reduction (R13, proven) ----
    #pragma unroll
    for (int g = 0; g < NG; ++g) sm.part[t][g] = acc_r[g].x + acc_r[g].y;
    sm.part[t][NG] = accl1.x + accl1.y;
    __syncthreads();

    const int blockOff = (blockIdx.x * NTHREADS) % K_SEG;  // k of thread 0

    for (int s = t; s < NSLOT; s += NTHREADS) {
        int kk, g;
        if (s < K_SEG * NG) { kk = s / NG; g = s % NG; }   // d-slot (k,g)
        else                { kk = s - K_SEG * NG; g = NG; } // l1-slot k
        int t0 = kk - blockOff; if (t0 < 0) t0 += K_SEG;
        float v = 0.0f;
        for (int tt = t0; tt < NTHREADS; tt += K_SEG)      // 12-13 contributors
            v += sm.part[tt][g];
        atomicAdd(&acc[s], v);        // device-scope, 336 addrs across LLC
    }

    // ---- last-block ticket -> finalize in the same dispatch ----
    __threadfence();                  // partial sums visible before ticket
    __syncthreads();
    if (t == 0) rank = atomicAdd(counter, 1u);
    __syncthreads();
    if (rank != NBLK - 1) return;     // not the last block

    __threadfence();
    for (int i = t; i < NSLOT; i += NTHREADS)
        s_acc[i] = atomicAdd(&acc[i], 0.0f);   // RMW read: never stale
    __syncthreads();

    const int G = *gpn_ptr;

    // per-k argmin over g (strict < == first-min, matches jnp.argmin).
    if (t < K_SEG) {
        const float B    = s_acc[K_SEG * NG + t];  // sum l1 for this k
        const float invn = 1.0f / (float)N_PIX;
        float best = INFINITY;
        int   bg   = 0;
        for (int g = 0; g < G && g < NG; ++g) {
            float ce = -(s_acc[t * NG + g] + B) * invn;
            if (ce < best) { best = ce; bg = g; }
        }
        ce_val[t]   = best;
        matching[t] = bg;
    }
    __syncthreads();

    if (t == 0) {
        int mx = 0;
        for (int kk = 0; kk < K_SEG; ++kk) mx = max(mx, matching[kk]);
        max_index_s = mx + 1;
    }
    // greedy dedup: per gt plane, first k with minimal ce_val among matched
    if (t < G && t < NG) {
        float best = BIGF;
        int   bk   = 0;               // all-BIG row -> index 0 (first-min)
        for (int kk = 0; kk < K_SEG; ++kk) {
            float vv = (matching[kk] == t) ? ce_val[kk] : BIGF;
            if (vv < best) { best = vv; bk = kk; }
        }
        best_k[t] = bk;
    }
    __syncthreads();

    if (t < K_SEG) {
        int m = matching[t];
        out[t] = (best_k[m] == t) ? m : max_index_s;
    }
}

extern "C" void kernel_launch(void* const* d_in, const int* in_sizes, int n_in,
                              void* d_out, int out_size, void* d_ws, size_t ws_size,
                              hipStream_t stream)
{
    const float* seg = (const float*)d_in[0];   // (230400, 21) fp32
    const int*   gt  = (const int*)  d_in[1];   // (21, 480, 480) int32
    const int*   gpn = (const int*)  d_in[2];   // scalar int (gt_plane_num)
    int*         out = (int*)d_out;             // (21,) int32

    float*        acc     = (float*)d_ws;                 // 336 floats
    unsigned int* counter = (unsigned int*)(acc + NSLOT); // 1 uint

    // zero acc + counter (graph-capture-safe, replaces the reduce dispatch)
    hipMemsetAsync(d_ws, 0, (NSLOT + 1) * sizeof(float), stream);
    ce_fused_kernel<<<NBLK, NTHREADS, 0, stream>>>(seg, gt, gpn, out,
                                                   acc, counter);
}

// Round 6
// 94.137 us; speedup vs baseline: 1.2922x; 1.2922x over previous
//
#include <hip/hip_runtime.h>

// MatchSegmentation, streaming formulation + two-stage reduction.
// ce[k,g] = -( sum_{n: gt=1} d[k,n] + sum_n l1[k,n] ) / N,  d = lp - l1.
// Accumulated in log2 domain (uniform positive scale preserves both argmins).
//
// R17: R16's fusion regressed (+29us: atomic tail + threadfence drain +
// ticket + memset dispatch) but exposed the kernel in rocprof for the first
// time: 425 GB/s (5.3% peak), VALUBusy 5.7%, Occupancy 16% -> stall-bound,
// all pipes idle. Little's law: 2 waves/SIMD (grid-limited) x 4 outstanding
// 4B loads = ~2MB in flight vs ~4-6MB needed at ~900cy cold latency.
// Fix (single change vs R14=92.6): issue the ENTIRE per-thread load set
// up-front -- 9 gt int4 stage loads, then ALL 40 seg loads fully unrolled
// into registers, pinned with sched_barrier(0). ~44 VMEM in flight/wave
// (vmcnt<=63), ~22MB device-wide -> HBM queues saturate immediately.
// VGPR ~110-130 is free (grid-limited to 2 blocks/CU; <=256 ok).
// Predict: accum ~35 -> 12-20us, total 92.6 -> 72-82us; accum hbm_gbps
// >=2000 if visible. If total >=90: theory dead, residual = SCLK ramp +
// fixed 43us harness fill -> declare floor.

#define N_PIX    230400
#define K_SEG    21
#define NG       15                 // gt_plane_num in this harness
#define NPB      (N_PIX / 4)        // 57600 pixel-blocks
#define NBLK     504                // R10: NBLK gradient bottoms here
#define NTHREADS 256
#define TOT_THR  (NBLK * NTHREADS)  // 129024
#define PB_STRIDE (TOT_THR / K_SEG) // 6144
#define NITER    10                 // ceil(NPB / PB_STRIDE)
#define NPB_BLK  14                 // distinct pb slots per block per iter
#define NSTAGE   (NITER * NG * NPB_BLK)              // 2100 staged int4
#define NSTG_R   ((NSTAGE + NTHREADS - 1) / NTHREADS) // 9 rounds
#define NSLOT    (K_SEG * NG + K_SEG)  // 315 d-sums ++ 21 l1-sums = 336
#define EPSF     1e-6f
#define BIGF     1.0e6f

typedef float f32x2 __attribute__((ext_vector_type(2)));
typedef float f32x4 __attribute__((ext_vector_type(4)));

__device__ __forceinline__ void pk_fma(f32x2& a, f32x2 m, f32x2 d) {
    // a += m * d, packed 2x fp32 in one instruction
    asm("v_pk_fma_f32 %0, %1, %2, %0" : "+v"(a) : "v"(m), "v"(d));
}

union SMem {
    f32x4 gtf[NITER][NG][NPB_BLK];   // 33.6 KB -- live in phase 1 only
    float part[NTHREADS][NG + 2];    // 17.4 KB -- live in phase 2 only
};

__global__ __launch_bounds__(NTHREADS, 2)
void ce_accum_kernel(const float* __restrict__ seg,    // (N, 21) fp32
                     const int*   __restrict__ gt,     // (21, N) int32 {0,1}
                     float*       __restrict__ partial) // [NBLK][NSLOT]
{
    __shared__ SMem sm;

    const int t    = threadIdx.x;
    const int u0   = blockIdx.x * NTHREADS + t;
    const int k    = u0 % K_SEG;                      // fixed per thread
    const int pbt  = u0 / K_SEG;                      // pb at j=0
    const int pb0b = (blockIdx.x * NTHREADS) / K_SEG; // block's first pb
    const int didx = pbt - pb0b;                      // 0..13, constant over j

    const int4* gt4 = (const int4*)gt;                // plane stride NPB int4s

    // ---- phase 0a: issue ALL gt stage loads (consumed first, pre-barrier) ----
    int4 gv[NSTG_R];
    #pragma unroll
    for (int r = 0; r < NSTG_R; ++r) {
        const int s = t + r * NTHREADS;
        int4 m = make_int4(0, 0, 0, 0);
        if (s < NSTAGE) {
            const int j = s / (NG * NPB_BLK);
            const int q = s % (NG * NPB_BLK);
            const int g = q / NPB_BLK;
            const int o = q % NPB_BLK;
            const int ps = pb0b + o + j * PB_STRIDE;
            if (ps < NPB) m = gt4[g * NPB + ps];      // coalesced 224B runs
        }
        gv[r] = m;
    }

    // ---- phase 0b: issue ALL 40 seg loads (deep MLP; the ~19MB seg stream
    //      hits the HBM queues immediately instead of 4-load quanta) ----
    float sv0[NITER], sv1[NITER], sv2[NITER], sv3[NITER];
    #pragma unroll
    for (int j = 0; j < NITER; ++j) {
        const int pbj  = pbt + j * PB_STRIDE;
        const int base = (pbj < NPB) ? (pbj * (4 * K_SEG) + k) : 0; // clamp safe
        sv0[j] = seg[base];
        sv1[j] = seg[base + K_SEG];
        sv2[j] = seg[base + 2 * K_SEG];
        sv3[j] = seg[base + 3 * K_SEG];
    }
    __builtin_amdgcn_sched_barrier(0);   // pin: no sinking of the loads above

    // ---- stage gt to LDS (vmcnt waits only on the gt group) ----
    f32x4* gf = (f32x4*)&sm.gtf[0][0][0];            // flat j-major == decode
    #pragma unroll
    for (int r = 0; r < NSTG_R; ++r) {
        const int s = t + r * NTHREADS;
        if (s < NSTAGE) {
            int4 m = gv[r];
            gf[s] = f32x4{(float)m.x, (float)m.y, (float)m.z, (float)m.w};
        }
    }

    f32x2 acc[NG];
    #pragma unroll
    for (int g = 0; g < NG; ++g) acc[g] = f32x2{0.0f, 0.0f};
    f32x2 accl1 = {0.0f, 0.0f};

    __syncthreads();                                  // gtf staged

    #pragma unroll
    for (int j = 0; j < NITER; ++j) {
        // only the last iteration can be dead (pbt <= 6143; 6143+8*6144 < NPB)
        const bool live = (j < NITER - 1) || (pbt + j * PB_STRIDE < NPB);
        if (live) {
            const float s0 = sv0[j], s1 = sv1[j], s2 = sv2[j], s3 = sv3[j];

            float lp0 = __log2f(s0 + EPSF), l10 = __log2f(1.0f - s0 + EPSF);
            float lp1 = __log2f(s1 + EPSF), l11 = __log2f(1.0f - s1 + EPSF);
            float lp2 = __log2f(s2 + EPSF), l12 = __log2f(1.0f - s2 + EPSF);
            float lp3 = __log2f(s3 + EPSF), l13 = __log2f(1.0f - s3 + EPSF);

            f32x2 d01 = {lp0 - l10, lp1 - l11};
            f32x2 d23 = {lp2 - l12, lp3 - l13};
            accl1 += f32x2{l10, l11};
            accl1 += f32x2{l12, l13};

            // 15 broadcast ds_read_b128 (single addr reg + imm offsets)
            #pragma unroll
            for (int g = 0; g < NG; ++g) {
                f32x4 mm = sm.gtf[j][g][didx];
                pk_fma(acc[g], mm.xy, d01);
                pk_fma(acc[g], mm.zw, d23);
            }
        }
    }

    __syncthreads();   // all gtf reads complete before aliased part writes

    // ---- non-atomic block reduction (R13, proven) ----
    #pragma unroll
    for (int g = 0; g < NG; ++g) sm.part[t][g] = acc[g].x + acc[g].y;
    sm.part[t][NG] = accl1.x + accl1.y;
    __syncthreads();

    const int blockOff = (blockIdx.x * NTHREADS) % K_SEG;  // k of thread 0
    float* dst = partial + (size_t)blockIdx.x * NSLOT;

    for (int s = t; s < NSLOT; s += NTHREADS) {
        int kk, g;
        if (s < K_SEG * NG) { kk = s / NG; g = s % NG; }   // d-slot (k,g)
        else                { kk = s - K_SEG * NG; g = NG; } // l1-slot k
        int t0 = kk - blockOff; if (t0 < 0) t0 += K_SEG;
        float v = 0.0f;
        for (int tt = t0; tt < NTHREADS; tt += K_SEG)      // 12-13 contributors
            v += sm.part[tt][g];
        dst[s] = v;                                        // coalesced store
    }
}

// 336 waves: wave s sums partial[b][s] over b in [0,NBLK), shuffle-reduce.
__global__ __launch_bounds__(256)
void reduce_kernel(const float* __restrict__ partial,  // [NBLK][NSLOT]
                   float*       __restrict__ acc)      // [NSLOT]
{
    const int s    = blockIdx.x * 4 + (threadIdx.x >> 6);  // slot 0..335
    const int lane = threadIdx.x & 63;

    float v = 0.0f;
    for (int b = lane; b < NBLK; b += 64)          // ~8 independent loads
        v += partial[(size_t)b * NSLOT + s];
    #pragma unroll
    for (int off = 32; off > 0; off >>= 1)
        v += __shfl_xor(v, off, 64);
    if (lane == 0) acc[s] = v;
}

__global__ void finalize_kernel(const float* __restrict__ acc,
                                const int*   __restrict__ gpn_ptr,
                                int*         __restrict__ out)
{
    __shared__ float ce_val  [K_SEG];
    __shared__ int   matching[K_SEG];
    __shared__ int   best_k  [NG];
    __shared__ int   max_index_s;

    const int G = *gpn_ptr;
    const int t = threadIdx.x;

    // per-k argmin over g (strict < == first-min, matches jnp.argmin).
    if (t < K_SEG) {
        const float B    = acc[K_SEG * NG + t];   // sum l1 for this k
        const float invn = 1.0f / (float)N_PIX;
        float best = INFINITY;
        int   bg   = 0;
        for (int g = 0; g < G && g < NG; ++g) {
            float ce = -(acc[t * NG + g] + B) * invn;
            if (ce < best) { best = ce; bg = g; }
        }
        ce_val[t]   = best;
        matching[t] = bg;
    }
    __syncthreads();

    if (t == 0) {
        int mx = 0;
        for (int kk = 0; kk < K_SEG; ++kk) mx = max(mx, matching[kk]);
        max_index_s = mx + 1;
    }
    // greedy dedup: per gt plane, first k with minimal ce_val among matched
    if (t < G && t < NG) {
        float best = BIGF;
        int   bk   = 0;               // all-BIG row -> index 0 (first-min)
        for (int kk = 0; kk < K_SEG; ++kk) {
            float v = (matching[kk] == t) ? ce_val[kk] : BIGF;
            if (v < best) { best = v; bk = kk; }
        }
        best_k[t] = bk;
    }
    __syncthreads();

    if (t < K_SEG) {
        int m = matching[t];
        out[t] = (best_k[m] == t) ? m : max_index_s;
    }
}

extern "C" void kernel_launch(void* const* d_in, const int* in_sizes, int n_in,
                              void* d_out, int out_size, void* d_ws, size_t ws_size,
                              hipStream_t stream)
{
    const float* seg = (const float*)d_in[0];   // (230400, 21) fp32
    const int*   gt  = (const int*)  d_in[1];   // (21, 480, 480) int32
    const int*   gpn = (const int*)  d_in[2];   // scalar int (gt_plane_num)
    int*         out = (int*)d_out;             // (21,) int32

    float* partial = (float*)d_ws;              // NBLK*NSLOT floats (~0.68 MB)
    float* acc     = partial + (size_t)NBLK * NSLOT;  // NSLOT floats

    ce_accum_kernel<<<NBLK, NTHREADS, 0, stream>>>(seg, gt, partial);
    reduce_kernel<<<NSLOT / 4, 256, 0, stream>>>(partial, acc);
    finalize_kernel<<<1, 64, 0, stream>>>(acc, gpn, out);
}